// Round 1
// baseline (1301.982 us; speedup 1.0000x reference)
//
#include <hip/hip_runtime.h>

#define B_N 32
#define T_N 2048
#define K_N 256

typedef _Float16 f16x8 __attribute__((ext_vector_type(8)));
typedef float f32x4 __attribute__((ext_vector_type(4)));

#define LN2x5 3.46573590280f          // 5*ln2 (damping 2^-5 per step, folded into exp arg)
#define C_ALL 7097.82712893f          // 2048 * 5 * ln2

// ---------- K1: per-(b,t) row max of y ----------
__global__ __launch_bounds__(256) void k_rowmax(const float* __restrict__ y,
                                                float* __restrict__ mx) {
  int row = blockIdx.x * 4 + (threadIdx.x >> 6);   // one wave per row
  int l = threadIdx.x & 63;
  const float4* p = (const float4*)(y + (size_t)row * K_N);
  float4 v = p[l];
  float m = fmaxf(fmaxf(v.x, v.y), fmaxf(v.z, v.w));
#pragma unroll
  for (int s = 1; s < 64; s <<= 1) m = fmaxf(m, __shfl_xor(m, s));
  if (l == 0) mx[row] = m;
}

// ---------- K2: ET[j][i] = exp(trans[i][j]) as f16 (transposed for B-frag loads) ----
__global__ __launch_bounds__(256) void k_expT(const float* __restrict__ trans,
                                              _Float16* __restrict__ ET) {
  int i = blockIdx.x;
  int j = threadIdx.x;
  ET[j * K_N + i] = (_Float16)__expf(trans[i * K_N + j]);
}

// ---------- K3: per-batch smx = sum_t mx, path = point + transition score ----------
__global__ __launch_bounds__(256) void k_scores(
    const float* __restrict__ y, const int* __restrict__ lab,
    const float* __restrict__ trans, const float* __restrict__ mx,
    float* __restrict__ smx, float* __restrict__ path) {
  const int b = blockIdx.x;
  const int tid = threadIdx.x;
  float s_mx = 0.f, s_pt = 0.f, s_tr = 0.f;
  for (int t = tid; t < T_N; t += 256) {
    s_mx += mx[b * T_N + t];
    int lt = lab[b * T_N + t];
    s_pt += y[((size_t)b * T_N + t) * K_N + lt];
    if (t < T_N - 1) {
      int lnx = lab[b * T_N + t + 1];
      s_tr += trans[lt * K_N + lnx];
    }
  }
#pragma unroll
  for (int s = 1; s < 64; s <<= 1) {
    s_mx += __shfl_xor(s_mx, s);
    s_pt += __shfl_xor(s_pt, s);
    s_tr += __shfl_xor(s_tr, s);
  }
  __shared__ float r0[4], r1[4], r2[4];
  int w = tid >> 6, l = tid & 63;
  if (l == 0) { r0[w] = s_mx; r1[w] = s_pt; r2[w] = s_tr; }
  __syncthreads();
  if (tid == 0) {
    smx[b] = r0[0] + r0[1] + r0[2] + r0[3];
    path[b] = (r1[0] + r1[1] + r1[2] + r1[3]) + (r2[0] + r2[1] + r2[2] + r2[3]);
  }
}

// ---------- main sequential forward: one block per batch ----------
__global__ __launch_bounds__(256, 1) void k_crf(
    const float* __restrict__ y, const _Float16* __restrict__ ET,
    const float* __restrict__ mx, const float* __restrict__ smx,
    const float* __restrict__ path, float* __restrict__ out) {
  const int b = blockIdx.x;
  const int tid = threadIdx.x;
  const int w = tid >> 6;     // wave: owns j in [64w, 64w+64)
  const int l = tid & 63;
  const int lr = l & 15;      // col within 16-tile
  const int lg = l >> 4;      // k-subgroup (8 elems each)

  alignas(16) __shared__ _Float16 vbuf[2][K_N];     // v as f16, double-buffered
  alignas(16) __shared__ float ystage[2][16][K_N];  // 16-step y staging, dbuf
  __shared__ float mstage[2][16];
  __shared__ float red[4];

  const float* __restrict__ yb = y + (size_t)b * T_N * K_N;
  const float* __restrict__ mxb = mx + b * T_N;

  // ---- persistent E B-fragments in VGPRs: B[k=i][c=j], k = kt*32 + lg*8 + e ----
  f16x8 Efrag[4][8];
  {
    const f16x8* ETv = (const f16x8*)ET;           // ET row j = 32 chunks of 8
#pragma unroll
    for (int jt = 0; jt < 4; ++jt) {
      int j = w * 64 + jt * 16 + lr;
#pragma unroll
      for (int kt = 0; kt < 8; ++kt)
        Efrag[jt][kt] = ETv[j * 32 + kt * 4 + lg];
    }
  }

  // ---- stage block 0 (t=0..15) ----
#pragma unroll
  for (int it = 0; it < 4; ++it) {
    int f = it * 1024 + tid * 4;
    *(float4*)((float*)&ystage[0][0][0] + f) = *(const float4*)(yb + f);
  }
  if (tid < 16) mstage[0][tid] = mxb[tid];
  __syncthreads();

  // ---- v0 = exp(y0 - mx0 - 5ln2) ----
  {
    float m0 = mstage[0][0];
#pragma unroll
    for (int jt = 0; jt < 4; ++jt) {
      int j = w * 64 + jt * 16 + lr;
      float v0 = __expf(ystage[0][0][j] - m0 - LN2x5);
      if (l < 16) vbuf[0][j] = (_Float16)v0;
    }
  }
  // ---- stage block 1 (t=16..31) ----
#pragma unroll
  for (int it = 0; it < 4; ++it) {
    int f = it * 1024 + tid * 4;
    *(float4*)((float*)&ystage[1][0][0] + f) = *(const float4*)(yb + 16 * K_N + f);
  }
  if (tid < 16) mstage[1][tid] = mxb[16 + tid];
  __syncthreads();

  float Cnorm = 0.0f;
  float wv0 = 0.f, wv1 = 0.f, wv2 = 0.f, wv3 = 0.f;

  for (int t = 1; t < T_N; ++t) {
    const int sb = t & 15;
    const int ybuf = (t >> 4) & 1;
    if (sb == 0) {                       // entering new 16-block: prefetch next
      int t0n = t + 16;
      if (t0n < T_N) {
#pragma unroll
        for (int it = 0; it < 4; ++it) {
          int f = it * 1024 + tid * 4;
          *(float4*)((float*)&ystage[ybuf ^ 1][0][0] + f) =
              *(const float4*)(yb + (size_t)t0n * K_N + f);
        }
        if (tid < 16) mstage[ybuf ^ 1][tid] = mxb[t0n + tid];
      }
    }

    // A fragments: broadcast v(t-1) into all 16 rows (k-index only)
    const f16x8* vv = (const f16x8*)&vbuf[(t - 1) & 1][0];
    f16x8 A[8];
#pragma unroll
    for (int kt = 0; kt < 8; ++kt) A[kt] = vv[kt * 4 + lg];

    // ex for this step (off mfma critical path)
    const float mxt = mstage[ybuf][sb];
    const float* yrow = &ystage[ybuf][sb][0];
    float ex0 = __expf(yrow[w * 64 + 0 + lr] - mxt - LN2x5);
    float ex1 = __expf(yrow[w * 64 + 16 + lr] - mxt - LN2x5);
    float ex2 = __expf(yrow[w * 64 + 32 + lr] - mxt - LN2x5);
    float ex3 = __expf(yrow[w * 64 + 48 + lr] - mxt - LN2x5);

    // u = v @ E  (every lane's reg0 ends up with u_{j(lane)})
    f32x4 a0 = {0.f, 0.f, 0.f, 0.f}, a1 = {0.f, 0.f, 0.f, 0.f};
    f32x4 a2 = {0.f, 0.f, 0.f, 0.f}, a3 = {0.f, 0.f, 0.f, 0.f};
#pragma unroll
    for (int kt = 0; kt < 8; ++kt) {
      a0 = __builtin_amdgcn_mfma_f32_16x16x32_f16(A[kt], Efrag[0][kt], a0, 0, 0, 0);
      a1 = __builtin_amdgcn_mfma_f32_16x16x32_f16(A[kt], Efrag[1][kt], a1, 0, 0, 0);
      a2 = __builtin_amdgcn_mfma_f32_16x16x32_f16(A[kt], Efrag[2][kt], a2, 0, 0, 0);
      a3 = __builtin_amdgcn_mfma_f32_16x16x32_f16(A[kt], Efrag[3][kt], a3, 0, 0, 0);
    }
    wv0 = a0[0] * ex0;
    wv1 = a1[0] * ex1;
    wv2 = a2[0] * ex2;
    wv3 = a3[0] * ex3;

    if ((t & 3) == 0) {                  // exact renormalize every 4 steps
      float m = fmaxf(fmaxf(wv0, wv1), fmaxf(wv2, wv3));
#pragma unroll
      for (int s = 1; s < 16; s <<= 1) m = fmaxf(m, __shfl_xor(m, s));
      if (l == 0) red[w] = m;
      __syncthreads();
      m = fmaxf(fmaxf(red[0], red[1]), fmaxf(red[2], red[3]));
      float r = 1.0f / m;
      Cnorm += __logf(m);
      wv0 *= r; wv1 *= r; wv2 *= r; wv3 *= r;
    }

    if (l < 16) {                        // store v(t) as f16
      _Float16* vd = &vbuf[t & 1][w * 64 + lr];
      vd[0]  = (_Float16)wv0;
      vd[16] = (_Float16)wv1;
      vd[32] = (_Float16)wv2;
      vd[48] = (_Float16)wv3;
    }
    __syncthreads();
  }

  // ---- final: log(sum_j v) + C - path ----
  float s = wv0 + wv1 + wv2 + wv3;
#pragma unroll
  for (int sh = 1; sh < 16; sh <<= 1) s += __shfl_xor(s, sh);
  if (l == 0) red[w] = s;
  __syncthreads();
  if (tid == 0) {
    float S = red[0] + red[1] + red[2] + red[3];
    out[b] = __logf(S) + Cnorm + smx[b] + C_ALL - path[b];
  }
}

extern "C" void kernel_launch(void* const* d_in, const int* in_sizes, int n_in,
                              void* d_out, int out_size, void* d_ws, size_t ws_size,
                              hipStream_t stream) {
  const float* y = (const float*)d_in[0];
  const float* trans = (const float*)d_in[1];
  const int* lab = (const int*)d_in[2];
  float* out = (float*)d_out;

  // workspace carve (~385 KB total)
  float* mx = (float*)d_ws;                                            // 65536 f32
  _Float16* ET = (_Float16*)((char*)d_ws + (size_t)B_N * T_N * 4);     // 65536 f16
  float* smx = (float*)((char*)d_ws + (size_t)B_N * T_N * 4 + (size_t)K_N * K_N * 2);
  float* path = smx + B_N;

  k_rowmax<<<dim3(B_N * T_N / 4), dim3(256), 0, stream>>>(y, mx);
  k_expT<<<dim3(K_N), dim3(K_N), 0, stream>>>(trans, ET);
  k_scores<<<dim3(B_N), dim3(256), 0, stream>>>(y, lab, trans, mx, smx, path);
  k_crf<<<dim3(B_N), dim3(256), 0, stream>>>(y, ET, mx, smx, path, out);
}

// Round 2
// 1133.948 us; speedup vs baseline: 1.1482x; 1.1482x over previous
//
#include <hip/hip_runtime.h>

#define B_N 32
#define T_N 2048
#define K_N 256

typedef _Float16 f16x8 __attribute__((ext_vector_type(8)));
typedef float f32x4 __attribute__((ext_vector_type(4)));

#define LN2x5 3.46573590280f          // 5*ln2 damping per step, folded into exp arg
#define C_ALL 7097.82712893f          // 2048 * 5 * ln2

// ---------- K1: per-(b,t) row max of y ----------
__global__ __launch_bounds__(256) void k_rowmax(const float* __restrict__ y,
                                                float* __restrict__ mx) {
  int row = blockIdx.x * 4 + (threadIdx.x >> 6);   // one wave per row
  int l = threadIdx.x & 63;
  const float4* p = (const float4*)(y + (size_t)row * K_N);
  float4 v = p[l];
  float m = fmaxf(fmaxf(v.x, v.y), fmaxf(v.z, v.w));
#pragma unroll
  for (int s = 1; s < 64; s <<= 1) m = fmaxf(m, __shfl_xor(m, s));
  if (l == 0) mx[row] = m;
}

// ---------- K2: ET[j][i] = exp(trans[i][j]) as f16 (transposed for B-frag loads) ----
__global__ __launch_bounds__(256) void k_expT(const float* __restrict__ trans,
                                              _Float16* __restrict__ ET) {
  int i = blockIdx.x;
  int j = threadIdx.x;
  ET[j * K_N + i] = (_Float16)__expf(trans[i * K_N + j]);
}

// ---------- K3: per-batch smx = sum_t mx, path = point + transition score ----------
__global__ __launch_bounds__(256) void k_scores(
    const float* __restrict__ y, const int* __restrict__ lab,
    const float* __restrict__ trans, const float* __restrict__ mx,
    float* __restrict__ smx, float* __restrict__ path) {
  const int b = blockIdx.x;
  const int tid = threadIdx.x;
  float s_mx = 0.f, s_pt = 0.f, s_tr = 0.f;
  for (int t = tid; t < T_N; t += 256) {
    s_mx += mx[b * T_N + t];
    int lt = lab[b * T_N + t];
    s_pt += y[((size_t)b * T_N + t) * K_N + lt];
    if (t < T_N - 1) {
      int lnx = lab[b * T_N + t + 1];
      s_tr += trans[lt * K_N + lnx];
    }
  }
#pragma unroll
  for (int s = 1; s < 64; s <<= 1) {
    s_mx += __shfl_xor(s_mx, s);
    s_pt += __shfl_xor(s_pt, s);
    s_tr += __shfl_xor(s_tr, s);
  }
  __shared__ float r0[4], r1[4], r2[4];
  int w = tid >> 6, l = tid & 63;
  if (l == 0) { r0[w] = s_mx; r1[w] = s_pt; r2[w] = s_tr; }
  __syncthreads();
  if (tid == 0) {
    smx[b] = r0[0] + r0[1] + r0[2] + r0[3];
    path[b] = (r1[0] + r1[1] + r1[2] + r1[3]) + (r2[0] + r2[1] + r2[2] + r2[3]);
  }
}

// ---------- main sequential forward: one block (4 waves) per batch ----------
// Per step critical path: ds_read A-frags -> 32 mfma -> mul -> ds_write_b16 ->
// lgkmcnt(0)+s_barrier (raw asm: NO vmcnt drain, y/mx prefetch stays in flight).
// Renorm every 4 steps with zero extra barriers: raw wave-max -> red[] before the
// step's own barrier; next step folds log(m) into the exp bias (applied once).
__global__ __launch_bounds__(256, 1) void k_crf(
    const float* __restrict__ y, const _Float16* __restrict__ ET,
    const float* __restrict__ mx, const float* __restrict__ smx,
    const float* __restrict__ path, float* __restrict__ out) {
  const int b = blockIdx.x;
  const int tid = threadIdx.x;
  const int w = tid >> 6;     // wave: owns cols [64w, 64w+64)
  const int l = tid & 63;
  const int lr = l & 15;      // col within 16-tile
  const int lg = (l >> 4) & 3;// k-subgroup / store-tile select

  alignas(16) __shared__ _Float16 vbuf[2][K_N];
  alignas(16) __shared__ float red[4];

  const float* __restrict__ yb = y + (size_t)b * T_N * K_N + w * 64 + lr;
  const float* __restrict__ mxb = mx + b * T_N;

  // ---- persistent E B-fragments in VGPRs (128 VGPR): B[k=i][c=j] ----
  f16x8 E0[8], E1[8], E2[8], E3[8];
  {
    const f16x8* ETv = (const f16x8*)ET;
#pragma unroll
    for (int kt = 0; kt < 8; ++kt) {
      E0[kt] = ETv[(w * 64 + 0 * 16 + lr) * 32 + kt * 4 + lg];
      E1[kt] = ETv[(w * 64 + 1 * 16 + lr) * 32 + kt * 4 + lg];
      E2[kt] = ETv[(w * 64 + 2 * 16 + lr) * 32 + kt * 4 + lg];
      E3[kt] = ETv[(w * 64 + 3 * 16 + lr) * 32 + kt * 4 + lg];
    }
  }

  // ---- v0 = exp(y0 - mx0 - 5ln2), all 64 lanes store one f16 ----
  {
    float m0 = mxb[0];
    float yv = y[(size_t)b * T_N * K_N + w * 64 + lg * 16 + lr];
    vbuf[0][w * 64 + lg * 16 + lr] = (_Float16)__expf(yv - m0 - LN2x5);
  }

  // ---- rotating 4-deep y/mx register prefetch ----
  float ys[4][4];
  float mxs[4];
#define PREF(P, TT) { int tp_ = (TT); tp_ = tp_ > (T_N - 1) ? (T_N - 1) : tp_; \
    const float* yp_ = yb + (size_t)tp_ * K_N;                                 \
    ys[P][0] = yp_[0];  ys[P][1] = yp_[16];                                    \
    ys[P][2] = yp_[32]; ys[P][3] = yp_[48];                                    \
    mxs[P] = mxb[tp_]; }

  PREF(0, 1) PREF(1, 2) PREF(2, 3) PREF(3, 4)

  float Cn = 0.0f;
  float wv0 = 0.f, wv1 = 0.f, wv2 = 0.f, wv3 = 0.f;

#define BARRIER asm volatile("s_waitcnt lgkmcnt(0)\ns_barrier" ::: "memory");

  BARRIER

#define STEP(TT, P, RB, WB, RENORM, APPLY, DO_STORE, DO_PREF, DO_BAR) {        \
    const f16x8* vv_ = (const f16x8*)&vbuf[RB][0];                             \
    f16x8 A_[8];                                                               \
    _Pragma("unroll")                                                          \
    for (int kt = 0; kt < 8; ++kt) A_[kt] = vv_[kt * 4 + lg];                  \
    float bias_ = mxs[P] + LN2x5;                                              \
    if (APPLY) {                                                               \
      f32x4 rv_ = *(const f32x4*)red;                                          \
      float mR_ = fmaxf(fmaxf(rv_[0], rv_[1]), fmaxf(rv_[2], rv_[3]));         \
      float lm_ = __logf(mR_);                                                 \
      Cn += lm_; bias_ += lm_;                                                 \
    }                                                                          \
    float e0_ = __expf(ys[P][0] - bias_);                                      \
    float e1_ = __expf(ys[P][1] - bias_);                                      \
    float e2_ = __expf(ys[P][2] - bias_);                                      \
    float e3_ = __expf(ys[P][3] - bias_);                                      \
    if (DO_PREF) PREF(P, (TT) + 4)                                             \
    f32x4 a0_ = {0.f, 0.f, 0.f, 0.f};                                          \
    f32x4 a1_ = a0_, a2_ = a0_, a3_ = a0_;                                     \
    _Pragma("unroll")                                                          \
    for (int kt = 0; kt < 8; ++kt) {                                           \
      a0_ = __builtin_amdgcn_mfma_f32_16x16x32_f16(A_[kt], E0[kt], a0_, 0, 0, 0); \
      a1_ = __builtin_amdgcn_mfma_f32_16x16x32_f16(A_[kt], E1[kt], a1_, 0, 0, 0); \
      a2_ = __builtin_amdgcn_mfma_f32_16x16x32_f16(A_[kt], E2[kt], a2_, 0, 0, 0); \
      a3_ = __builtin_amdgcn_mfma_f32_16x16x32_f16(A_[kt], E3[kt], a3_, 0, 0, 0); \
    }                                                                          \
    wv0 = a0_[0] * e0_; wv1 = a1_[0] * e1_;                                    \
    wv2 = a2_[0] * e2_; wv3 = a3_[0] * e3_;                                    \
    if (RENORM) {                                                              \
      float ml_ = fmaxf(fmaxf(wv0, wv1), fmaxf(wv2, wv3));                     \
      ml_ = fmaxf(ml_, __shfl_xor(ml_, 1));                                    \
      ml_ = fmaxf(ml_, __shfl_xor(ml_, 2));                                    \
      ml_ = fmaxf(ml_, __shfl_xor(ml_, 4));                                    \
      ml_ = fmaxf(ml_, __shfl_xor(ml_, 8));                                    \
      if (l == 0) red[w] = ml_;                                                \
    }                                                                          \
    if (DO_STORE) {                                                            \
      float sv_ = lg == 0 ? wv0 : lg == 1 ? wv1 : lg == 2 ? wv2 : wv3;         \
      vbuf[WB][w * 64 + lg * 16 + lr] = (_Float16)sv_;                         \
    }                                                                          \
    if (DO_BAR) BARRIER                                                        \
  }

  // first 4 steps peeled (no APPLY at t=1)
  STEP(1, 0, 0, 1, 0, 0, 1, 1, 1)
  STEP(2, 1, 1, 0, 0, 0, 1, 1, 1)
  STEP(3, 2, 0, 1, 0, 0, 1, 1, 1)
  STEP(4, 3, 1, 0, 1, 0, 1, 1, 1)

#pragma unroll 1
  for (int t0 = 5; t0 <= T_N - 7; t0 += 4) {   // t0 = 5..2041, covers t=5..2044
    STEP(t0,     0, 0, 1, 0, 1, 1, 1, 1)
    STEP(t0 + 1, 1, 1, 0, 0, 0, 1, 1, 1)
    STEP(t0 + 2, 2, 0, 1, 0, 0, 1, 1, 1)
    STEP(t0 + 3, 3, 1, 0, 1, 0, 1, 1, 1)
  }

  // epilogue t=2045..2047 (slots already prefetched by last iteration)
  STEP(2045, 0, 0, 1, 0, 1, 1, 0, 1)
  STEP(2046, 1, 1, 0, 0, 0, 1, 0, 1)
  STEP(2047, 2, 0, 1, 0, 0, 0, 0, 0)

  // ---- final: log(sum_j v_raw) + Cn + smx + C_ALL - path ----
  float s = wv0 + wv1 + wv2 + wv3;
  s += __shfl_xor(s, 1);
  s += __shfl_xor(s, 2);
  s += __shfl_xor(s, 4);
  s += __shfl_xor(s, 8);
  if (l == 0) red[w] = s;
  BARRIER
  if (tid == 0) {
    float S = red[0] + red[1] + red[2] + red[3];
    out[b] = __logf(S) + Cn + smx[b] + C_ALL - path[b];
  }
}

extern "C" void kernel_launch(void* const* d_in, const int* in_sizes, int n_in,
                              void* d_out, int out_size, void* d_ws, size_t ws_size,
                              hipStream_t stream) {
  const float* y = (const float*)d_in[0];
  const float* trans = (const float*)d_in[1];
  const int* lab = (const int*)d_in[2];
  float* out = (float*)d_out;

  // workspace carve (~385 KB total)
  float* mx = (float*)d_ws;                                            // B*T f32
  _Float16* ET = (_Float16*)((char*)d_ws + (size_t)B_N * T_N * 4);     // K*K f16
  float* smx = (float*)((char*)d_ws + (size_t)B_N * T_N * 4 + (size_t)K_N * K_N * 2);
  float* path = smx + B_N;

  k_rowmax<<<dim3(B_N * T_N / 4), dim3(256), 0, stream>>>(y, mx);
  k_expT<<<dim3(K_N), dim3(K_N), 0, stream>>>(trans, ET);
  k_scores<<<dim3(B_N), dim3(256), 0, stream>>>(y, lab, trans, mx, smx, path);
  k_crf<<<dim3(B_N), dim3(256), 0, stream>>>(y, ET, mx, smx, path, out);
}

// Round 3
// 1133.883 us; speedup vs baseline: 1.1483x; 1.0001x over previous
//
#include <hip/hip_runtime.h>

#define B_N 32
#define T_N 2048
#define K_N 256

typedef float f32x4 __attribute__((ext_vector_type(4)));
typedef int i32x8 __attribute__((ext_vector_type(8)));

// fp8 MX mfma, scales = 1.0 (e8m0 biased 127 in every byte)
#define MFMA8(A, B, C) \
  __builtin_amdgcn_mfma_scale_f32_16x16x128_f8f6f4((A), (B), (C), 0, 0, 0, 0x7F7F7F7F, 0, 0x7F7F7F7F)

// ---------- K1: per-(b,t) row max of y ----------
__global__ __launch_bounds__(256) void k_rowmax(const float* __restrict__ y,
                                                float* __restrict__ mx) {
  int row = blockIdx.x * 4 + (threadIdx.x >> 6);   // one wave per row
  int l = threadIdx.x & 63;
  const float4* p = (const float4*)(y + (size_t)row * K_N);
  float4 v = p[l];
  float m = fmaxf(fmaxf(v.x, v.y), fmaxf(v.z, v.w));
#pragma unroll
  for (int s = 1; s < 64; s <<= 1) m = fmaxf(m, __shfl_xor(m, s));
  if (l == 0) mx[row] = m;
}

// ---------- K2: GT[j][i] = fp8_e4m3(exp(trans[i][j]) - 1)  (g-matrix, transposed) ----
__global__ __launch_bounds__(256) void k_g8(const float* __restrict__ trans,
                                            unsigned char* __restrict__ GT) {
  int j = blockIdx.x;     // output col
  int i = threadIdx.x;    // k index
  float g = __expf(trans[i * K_N + j]) - 1.0f;
  int pk = __builtin_amdgcn_cvt_pk_fp8_f32(g, 0.f, 0, false);
  GT[j * K_N + i] = (unsigned char)(pk & 0xff);
}

// ---------- K3: per-batch smx = sum_t mx, path = point + transition score ----------
__global__ __launch_bounds__(256) void k_scores(
    const float* __restrict__ y, const int* __restrict__ lab,
    const float* __restrict__ trans, const float* __restrict__ mx,
    float* __restrict__ smx, float* __restrict__ path) {
  const int b = blockIdx.x;
  const int tid = threadIdx.x;
  float s_mx = 0.f, s_pt = 0.f, s_tr = 0.f;
  for (int t = tid; t < T_N; t += 256) {
    s_mx += mx[b * T_N + t];
    int lt = lab[b * T_N + t];
    s_pt += y[((size_t)b * T_N + t) * K_N + lt];
    if (t < T_N - 1) {
      int lnx = lab[b * T_N + t + 1];
      s_tr += trans[lt * K_N + lnx];
    }
  }
#pragma unroll
  for (int s = 1; s < 64; s <<= 1) {
    s_mx += __shfl_xor(s_mx, s);
    s_pt += __shfl_xor(s_pt, s);
    s_tr += __shfl_xor(s_tr, s);
  }
  __shared__ float r0[4], r1[4], r2[4];
  int w = tid >> 6, l = tid & 63;
  if (l == 0) { r0[w] = s_mx; r1[w] = s_pt; r2[w] = s_tr; }
  __syncthreads();
  if (tid == 0) {
    smx[b] = r0[0] + r0[1] + r0[2] + r0[3];
    path[b] = (r1[0] + r1[1] + r1[2] + r1[3]) + (r2[0] + r2[1] + r2[2] + r2[3]);
  }
}

// ---------- main sequential forward: one block (4 waves) per batch ----------
// Linear-space recurrence with E = 1 + g:  u = S(t-1) + v8 . g8  (fp8 K=128 mfma),
// w_j = (S + u_j) * exp(y_j - mx_t - log S(t-1)).  Stored v in [0, 1.05] (e4m3-safe,
// overflow-free by construction).  Cn accumulates log S each step.
__global__ __launch_bounds__(256, 1) void k_crf(
    const float* __restrict__ y, const unsigned char* __restrict__ GT,
    const float* __restrict__ mx, const float* __restrict__ smx,
    const float* __restrict__ path, float* __restrict__ out) {
  const int b = blockIdx.x;
  const int tid = threadIdx.x;
  const int w = tid >> 6;      // wave: owns cols [64w, 64w+64)
  const int l = tid & 63;
  const int lr = l & 15;       // col within 16-tile
  const int lg = (l >> 4) & 3; // k-subgroup (32 fp8 each per 128-k half)

  alignas(64) __shared__ unsigned char vbuf8[2][K_N];   // v as e4m3, double-buffered
  alignas(16) __shared__ float red2[2][4];              // per-wave partial sums, parity dbuf

  const float* __restrict__ yb = y + (size_t)b * T_N * K_N + w * 64 + lr;
  const float* __restrict__ mxb = mx + b * T_N;

  // ---- persistent g8 B-fragments (4 col-tiles x 2 k-halves x 8 dwords = 64 VGPR) ----
  i32x8 Bf[4][2];
#pragma unroll
  for (int tt = 0; tt < 4; ++tt) {
#pragma unroll
    for (int h = 0; h < 2; ++h)
      Bf[tt][h] = *(const i32x8*)(GT + (size_t)(w * 64 + tt * 16 + lr) * K_N + h * 128 + lg * 32);
  }

  // ---- v0 = exp(y0 - mx0)  (max entry = 1.0: full e4m3 precision band) ----
  {
    int c0 = w * 64 + lg * 16 + lr;
    float v0 = __expf(y[(size_t)b * T_N * K_N + c0] - mxb[0]);
    int pk = __builtin_amdgcn_cvt_pk_fp8_f32(v0, 0.f, 0, false);
    vbuf8[0][c0] = (unsigned char)(pk & 0xff);
    float ps = v0;   // all 64 lanes hold distinct cols here: full-wave sum
#pragma unroll
    for (int s = 1; s < 64; s <<= 1) ps += __shfl_xor(ps, s);
    if (l == 0) red2[0][w] = ps;
  }

  // ---- rotating 4-deep y/mx register prefetch ----
  float ys[4][4];
  float mxs[4];
#define PREF(P, TT) { int tp_ = (TT); tp_ = tp_ > (T_N - 1) ? (T_N - 1) : tp_; \
    const float* yp_ = yb + (size_t)tp_ * K_N;                                 \
    ys[P][0] = yp_[0];  ys[P][1] = yp_[16];                                    \
    ys[P][2] = yp_[32]; ys[P][3] = yp_[48];                                    \
    mxs[P] = mxb[tp_]; }

  PREF(0, 1) PREF(1, 2) PREF(2, 3) PREF(3, 4)

  float Cn = 0.0f;
  float wv0 = 0.f, wv1 = 0.f, wv2 = 0.f, wv3 = 0.f;

#define BARRIER asm volatile("s_waitcnt lgkmcnt(0)\ns_barrier" ::: "memory");

  BARRIER

#define STEP(TT, P, RB, WB, DO_PREF) {                                         \
    f32x4 r_ = *(const f32x4*)(&red2[((TT) - 1) & 1][0]);                      \
    i32x8 A0_ = *(const i32x8*)(&vbuf8[RB][lg * 32]);                          \
    i32x8 A1_ = *(const i32x8*)(&vbuf8[RB][128 + lg * 32]);                    \
    float Sp_ = (r_[0] + r_[1]) + (r_[2] + r_[3]);                             \
    float ls_ = __logf(Sp_);                                                   \
    float bias_ = mxs[P] + ls_;                                                \
    float e0_ = __expf(ys[P][0] - bias_);                                      \
    float e1_ = __expf(ys[P][1] - bias_);                                      \
    float e2_ = __expf(ys[P][2] - bias_);                                      \
    float e3_ = __expf(ys[P][3] - bias_);                                      \
    if (DO_PREF) PREF(P, (TT) + 4)                                             \
    f32x4 z_ = {0.f, 0.f, 0.f, 0.f};                                           \
    f32x4 a0_ = MFMA8(A1_, Bf[0][1], MFMA8(A0_, Bf[0][0], z_));                \
    f32x4 a1_ = MFMA8(A1_, Bf[1][1], MFMA8(A0_, Bf[1][0], z_));                \
    f32x4 a2_ = MFMA8(A1_, Bf[2][1], MFMA8(A0_, Bf[2][0], z_));                \
    f32x4 a3_ = MFMA8(A1_, Bf[3][1], MFMA8(A0_, Bf[3][0], z_));                \
    wv0 = (Sp_ + a0_[0]) * e0_;                                                \
    wv1 = (Sp_ + a1_[0]) * e1_;                                                \
    wv2 = (Sp_ + a2_[0]) * e2_;                                                \
    wv3 = (Sp_ + a3_[0]) * e3_;                                                \
    Cn += ls_;                                                                 \
    float ps_ = (wv0 + wv1) + (wv2 + wv3);                                     \
    ps_ += __shfl_xor(ps_, 1);                                                 \
    ps_ += __shfl_xor(ps_, 2);                                                 \
    ps_ += __shfl_xor(ps_, 4);                                                 \
    ps_ += __shfl_xor(ps_, 8);                                                 \
    if (l == 0) red2[(TT) & 1][w] = ps_;                                       \
    {                                                                          \
      float sv_ = lg == 0 ? wv0 : lg == 1 ? wv1 : lg == 2 ? wv2 : wv3;         \
      int pk_ = __builtin_amdgcn_cvt_pk_fp8_f32(sv_, 0.f, 0, false);           \
      vbuf8[WB][w * 64 + lg * 16 + lr] = (unsigned char)(pk_ & 0xff);          \
    }                                                                          \
    BARRIER                                                                    \
  }

#pragma unroll 1
  for (int t0 = 1; t0 <= T_N - 7; t0 += 4) {   // t0 = 1,5,...,2041 -> t = 1..2044
    STEP(t0,     0, 0, 1, 1)
    STEP(t0 + 1, 1, 1, 0, 1)
    STEP(t0 + 2, 2, 0, 1, 1)
    STEP(t0 + 3, 3, 1, 0, 1)
  }
  // tail: t = 2045 (P0), 2046 (P1), 2047 (P2)
  STEP(2045, 0, 0, 1, 0)
  STEP(2046, 1, 1, 0, 0)
  STEP(2047, 2, 0, 1, 0)

  // ---- final: log(sum_j v_T) + Cn + smx - path ----
  if (tid == 0) {
    float S = (red2[1][0] + red2[1][1]) + (red2[1][2] + red2[1][3]);  // 2047 & 1 == 1
    out[b] = __logf(S) + Cn + smx[b] - path[b];
  }
}

extern "C" void kernel_launch(void* const* d_in, const int* in_sizes, int n_in,
                              void* d_out, int out_size, void* d_ws, size_t ws_size,
                              hipStream_t stream) {
  const float* y = (const float*)d_in[0];
  const float* trans = (const float*)d_in[1];
  const int* lab = (const int*)d_in[2];
  float* out = (float*)d_out;

  // workspace carve (~321 KB total)
  float* mx = (float*)d_ws;                                              // B*T f32
  unsigned char* GT = (unsigned char*)d_ws + (size_t)B_N * T_N * 4;      // K*K fp8
  float* smx = (float*)((char*)d_ws + (size_t)B_N * T_N * 4 + (size_t)K_N * K_N);
  float* path = smx + B_N;

  k_rowmax<<<dim3(B_N * T_N / 4), dim3(256), 0, stream>>>(y, mx);
  k_g8<<<dim3(K_N), dim3(256), 0, stream>>>(trans, GT);
  k_scores<<<dim3(B_N), dim3(256), 0, stream>>>(y, lab, trans, mx, smx, path);
  k_crf<<<dim3(B_N), dim3(256), 0, stream>>>(y, GT, mx, smx, path, out);
}

// Round 4
// 969.651 us; speedup vs baseline: 1.3427x; 1.1694x over previous
//
#include <hip/hip_runtime.h>

#define B_N 32
#define T_N 2048
#define K_N 256

typedef float f32x4 __attribute__((ext_vector_type(4)));
typedef int i32x8 __attribute__((ext_vector_type(8)));

// fp8 MX mfma, scales = 1.0 (e8m0 biased 127 in every byte)
#define MFMA8(A, B, C) \
  __builtin_amdgcn_mfma_scale_f32_16x16x128_f8f6f4((A), (B), (C), 0, 0, 0, 0x7F7F7F7F, 0, 0x7F7F7F7F)

// ---------- K1 fused: rowmax (blocks 0..B*T/4-1) + g8 (next 256 blocks) ----------
__global__ __launch_bounds__(256) void k_prep(const float* __restrict__ y,
                                              float* __restrict__ mx,
                                              const float* __restrict__ trans,
                                              unsigned char* __restrict__ GT) {
  int blk = blockIdx.x;
  if (blk < B_N * T_N / 4) {
    int row = blk * 4 + (threadIdx.x >> 6);
    int l = threadIdx.x & 63;
    const float4* p = (const float4*)(y + (size_t)row * K_N);
    float4 v = p[l];
    float m = fmaxf(fmaxf(v.x, v.y), fmaxf(v.z, v.w));
#pragma unroll
    for (int s = 1; s < 64; s <<= 1) m = fmaxf(m, __shfl_xor(m, s));
    if (l == 0) mx[row] = m;
  } else {
    int j = blk - B_N * T_N / 4;   // output col
    int i = threadIdx.x;           // k index
    float g = __expf(trans[i * K_N + j]) - 1.0f;
    int pk = __builtin_amdgcn_cvt_pk_fp8_f32(g, 0.f, 0, false);
    GT[j * K_N + i] = (unsigned char)(pk & 0xff);
  }
}

// ---------- main sequential forward: one block (4 waves) per batch ----------
// u_j = Sp + v.g_j  (fp8 K=128 mfma);  Sp = v.1 via all-ones fp8 mfma (no shuffles).
// Renorm by 2^-E (E = exponent of Sp): 2 int ops; Cn = (sum E)*ln2 exact.
// Per-lane: one y element, one stored fp8 byte. path/smx fused in.
__global__ __launch_bounds__(256, 1) void k_crf(
    const float* __restrict__ y, const unsigned char* __restrict__ GT,
    const float* __restrict__ mx, const int* __restrict__ lab,
    const float* __restrict__ trans, float* __restrict__ out) {
  const int b = blockIdx.x;
  const int tid = threadIdx.x;
  const int w = tid >> 6;      // wave: owns cols [64w, 64w+64)
  const int l = tid & 63;
  const int lr = l & 15;       // col within 16-tile
  const int lg = (l >> 4) & 3; // k-subgroup (32 fp8 per 128-k half)
  const int mycol = w * 64 + lg * 16 + lr;

  alignas(64) __shared__ unsigned char vbuf8[2][K_N];
  __shared__ float red[4];
  __shared__ float pr[8];

  const float* __restrict__ ybase = y + (size_t)b * T_N * K_N;
  const float* __restrict__ ybl = ybase + mycol;      // per-lane column
  const float* __restrict__ mxb = mx + b * T_N;

  // ---- prologue: path score (point + transition), fused from old k_scores ----
  {
    float s_pt = 0.f, s_tr = 0.f;
    const int* lb = lab + b * T_N;
    for (int t = tid; t < T_N; t += 256) {
      int lt = lb[t];
      s_pt += ybase[(size_t)t * K_N + lt];
      if (t < T_N - 1) s_tr += trans[lt * K_N + lb[t + 1]];
    }
    float s_ = s_pt + s_tr;
#pragma unroll
    for (int s = 1; s < 64; s <<= 1) s_ += __shfl_xor(s_, s);
    if (l == 0) pr[w] = s_;
  }

  // ---- persistent g8 B-fragments (64 VGPR) + all-ones fragment ----
  i32x8 Bf[4][2];
#pragma unroll
  for (int tt = 0; tt < 4; ++tt) {
#pragma unroll
    for (int h = 0; h < 2; ++h)
      Bf[tt][h] = *(const i32x8*)(GT + (size_t)(w * 64 + tt * 16 + lr) * K_N + h * 128 + lg * 32);
  }
  i32x8 Bones;
#pragma unroll
  for (int q = 0; q < 8; ++q) Bones[q] = 0x38383838;   // e4m3 1.0 bytes

  // ---- v0 = exp(y0 - mx0), one byte per lane ----
  float mx0 = mxb[0];
  {
    float v0 = __expf(ybl[0] - mx0);
    int pk = __builtin_amdgcn_cvt_pk_fp8_f32(v0, 0.f, 0, false);
    vbuf8[0][mycol] = (unsigned char)(pk & 0xff);
  }

  // ---- rotating 4-deep per-lane y/mx prefetch ----
  float ys[4];
  float mxs[4];
#define PREF(P, TT) { int tp_ = (TT); tp_ = tp_ > (T_N - 1) ? (T_N - 1) : tp_; \
    ys[P] = ybl[(size_t)tp_ * K_N]; mxs[P] = mxb[tp_]; }

  PREF(0, 1) PREF(1, 2) PREF(2, 3) PREF(3, 4)

  int Eacc = 0;
  float smx_acc = mx0;
  float svf = 0.f;

#define BARRIER asm volatile("s_waitcnt lgkmcnt(0)\ns_barrier" ::: "memory");

  BARRIER

#define STEP(TT, P, RB, WB, DO_PREF) {                                         \
    const i32x8* va_ = (const i32x8*)&vbuf8[RB][0];                            \
    i32x8 A0_ = va_[lg];                                                       \
    i32x8 A1_ = va_[4 + lg];                                                   \
    float e_ = __expf(ys[P] - mxs[P]);                                         \
    smx_acc += mxs[P];                                                         \
    if (DO_PREF) PREF(P, (TT) + 4)                                             \
    f32x4 z_ = {0.f, 0.f, 0.f, 0.f};                                           \
    f32x4 s0_ = MFMA8(A0_, Bones, z_);                                         \
    f32x4 s1_ = MFMA8(A1_, Bones, z_);                                         \
    f32x4 a0l_ = MFMA8(A0_, Bf[0][0], z_);                                     \
    f32x4 a0h_ = MFMA8(A1_, Bf[0][1], z_);                                     \
    f32x4 a1l_ = MFMA8(A0_, Bf[1][0], z_);                                     \
    f32x4 a1h_ = MFMA8(A1_, Bf[1][1], z_);                                     \
    f32x4 a2l_ = MFMA8(A0_, Bf[2][0], z_);                                     \
    f32x4 a2h_ = MFMA8(A1_, Bf[2][1], z_);                                     \
    f32x4 a3l_ = MFMA8(A0_, Bf[3][0], z_);                                     \
    f32x4 a3h_ = MFMA8(A1_, Bf[3][1], z_);                                     \
    float Sp_ = s0_[0] + s1_[0];                                               \
    int sb_ = __float_as_int(Sp_) & 0x7f800000;                                \
    float rS_ = __int_as_float(0x7F000000 - sb_);                              \
    Eacc += (sb_ >> 23);                                                       \
    float er_ = e_ * rS_;                                                      \
    float ol_ = lg == 0 ? a0l_[0] : lg == 1 ? a1l_[0] : lg == 2 ? a2l_[0] : a3l_[0]; \
    float oh_ = lg == 0 ? a0h_[0] : lg == 1 ? a1h_[0] : lg == 2 ? a2h_[0] : a3h_[0]; \
    float wv_ = (Sp_ + (ol_ + oh_)) * er_;                                     \
    int pk_ = __builtin_amdgcn_cvt_pk_fp8_f32(wv_, 0.f, 0, false);             \
    vbuf8[WB][mycol] = (unsigned char)(pk_ & 0xff);                            \
    svf = wv_;                                                                 \
    BARRIER                                                                    \
  }

#pragma unroll 1
  for (int t0 = 1; t0 <= T_N - 7; t0 += 4) {   // t0 = 1,5,...,2041 -> t = 1..2044
    STEP(t0,     0, 0, 1, 1)
    STEP(t0 + 1, 1, 1, 0, 1)
    STEP(t0 + 2, 2, 0, 1, 1)
    STEP(t0 + 3, 3, 1, 0, 1)
  }
  // tail: t = 2045 (P0), 2046 (P1), 2047 (P2)
  STEP(2045, 0, 0, 1, 0)
  STEP(2046, 1, 1, 0, 0)
  STEP(2047, 2, 0, 1, 0)

  // ---- final: log(sum_j v_T) + Cn + smx - path ----
  {
    float s = svf;
#pragma unroll
    for (int sh = 1; sh < 64; sh <<= 1) s += __shfl_xor(s, sh);
    if (l == 0) red[w] = s;
  }
  BARRIER
  if (tid == 0) {
    float S = (red[0] + red[1]) + (red[2] + red[3]);
    float Cn = (float)(Eacc - 127 * (T_N - 1)) * 0.69314718056f;
    float path = (pr[0] + pr[1]) + (pr[2] + pr[3]);
    out[b] = __logf(S) + Cn + smx_acc - path;
  }
}

extern "C" void kernel_launch(void* const* d_in, const int* in_sizes, int n_in,
                              void* d_out, int out_size, void* d_ws, size_t ws_size,
                              hipStream_t stream) {
  const float* y = (const float*)d_in[0];
  const float* trans = (const float*)d_in[1];
  const int* lab = (const int*)d_in[2];
  float* out = (float*)d_out;

  // workspace carve (~320 KB)
  float* mx = (float*)d_ws;                                           // B*T f32
  unsigned char* GT = (unsigned char*)d_ws + (size_t)B_N * T_N * 4;   // K*K fp8

  k_prep<<<dim3(B_N * T_N / 4 + K_N), dim3(256), 0, stream>>>(y, mx, trans, GT);
  k_crf<<<dim3(B_N), dim3(256), 0, stream>>>(y, GT, mx, lab, trans, out);
}